// Round 3
// baseline (1247.443 us; speedup 1.0000x reference)
//
#include <hip/hip_runtime.h>
#include <stdint.h>

#define DEV static __device__ __forceinline__

typedef __attribute__((ext_vector_type(8))) __bf16 bf16x8;
typedef __attribute__((ext_vector_type(4))) float f32x4;

// ---------- bf16 helpers ----------
DEV float b2f(unsigned short u) {
    union { unsigned int i; float f; } v; v.i = ((unsigned int)u) << 16; return v.f;
}
DEV unsigned short f2b(float f) {
    unsigned int u = __builtin_bit_cast(unsigned int, f);
    unsigned int r = (u + 0x7FFFu + ((u >> 16) & 1u)) >> 16;  // RNE
    return (unsigned short)r;
}

// ---------- async global->LDS, 16B per lane ----------
DEV void gload16(const void* g, void* l) {
    __builtin_amdgcn_global_load_lds(
        (const __attribute__((address_space(1))) void*)g,
        (__attribute__((address_space(3))) void*)l, 16, 0, 0);
}

// ============ kernel 0: fp32 -> bf16 copy (n multiple of 2048) ==============
__global__ __launch_bounds__(256) void k_cvt(
    const float* __restrict__ src, unsigned short* __restrict__ dst)
{
    long i = ((long)blockIdx.x * 256 + threadIdx.x) * 8;
    float4 a = *(const float4*)(src + i);
    float4 b = *(const float4*)(src + i + 4);
    union { uint4 v; unsigned short s[8]; } o;
    o.s[0] = f2b(a.x); o.s[1] = f2b(a.y); o.s[2] = f2b(a.z); o.s[3] = f2b(a.w);
    o.s[4] = f2b(b.x); o.s[5] = f2b(b.y); o.s[6] = f2b(b.z); o.s[7] = f2b(b.w);
    *(uint4*)(dst + i) = o.v;
}

// ================== kernel 1: RMSNorm of hidden -> u (bf16) =================
// rows = 4096 (b*l), dim 2048. block 256, 8 elems/thread. fp32 in, bf16 out.
__global__ __launch_bounds__(256) void k_rmsnorm_in(
    const float* __restrict__ h, const float* __restrict__ w,
    unsigned short* __restrict__ u)
{
    int row = blockIdx.x, t = threadIdx.x;
    const float* hp = h + (long)row * 2048 + t * 8;
    float4 a = *(const float4*)hp;
    float4 b = *(const float4*)(hp + 4);
    float x[8] = {a.x, a.y, a.z, a.w, b.x, b.y, b.z, b.w};
    float ss = 0.f;
#pragma unroll
    for (int i = 0; i < 8; i++) ss += x[i] * x[i];
#pragma unroll
    for (int o = 32; o > 0; o >>= 1) ss += __shfl_down(ss, o);
    __shared__ float red[4];
    if ((t & 63) == 0) red[t >> 6] = ss;
    __syncthreads();
    float tot = red[0] + red[1] + red[2] + red[3];
    float scale = rsqrtf(tot * (1.0f / 2048.0f) + 1e-5f);
    float4 wa = *(const float4*)(w + t * 8);
    float4 wb = *(const float4*)(w + t * 8 + 4);
    float wv[8] = {wa.x, wa.y, wa.z, wa.w, wb.x, wb.y, wb.z, wb.w};
    union { uint4 v; unsigned short s[8]; } ow;
#pragma unroll
    for (int i = 0; i < 8; i++) ow.s[i] = f2b(x[i] * scale * wv[i]);
    *(uint4*)(u + (long)row * 2048 + t * 8) = ow.v;
}

// ================== GEMM: C[MxN] = A[MxK] * B[NxK]^T (bf16 in, fp32 acc) ====
// m97 structure: 128x128 tile, BK=32, 4 waves (2x2), 16x16x32 MFMA, 4x4 frags.
// B rows clamped to nvalid (last tile may be partial); stores guarded.
// EPI 0: store bf16 to Cb.  EPI 1: store fp32 (acc + fp32 Res) to Cf.
template <int EPI>
__global__ __launch_bounds__(256) void k_gemm_bt(
    const unsigned short* __restrict__ A, const unsigned short* __restrict__ Bm,
    int K, int nvalid, unsigned short* __restrict__ Cb, float* __restrict__ Cf,
    int ldc, const float* __restrict__ Res)
{
    __shared__ __align__(16) unsigned short sA[128 * 32];
    __shared__ __align__(16) unsigned short sB[128 * 32];
    int t = threadIdx.x;
    int w = t >> 6, L = t & 63;
    long m0 = (long)blockIdx.y * 128, n0 = (long)blockIdx.x * 128;

    int rS = w * 32 + (L >> 2);      // staging row in tile
    int cS = (L & 3) * 8;            // staging col (elems)
    long rB0 = n0 + rS;       if (rB0 >= nvalid) rB0 = nvalid - 1;
    long rB1 = n0 + rS + 16;  if (rB1 >= nvalid) rB1 = nvalid - 1;
    const unsigned short* gA0 = A + (m0 + rS) * K + cS;
    const unsigned short* gA1 = gA0 + 16L * K;
    const unsigned short* gB0 = Bm + rB0 * K + cS;
    const unsigned short* gB1 = Bm + rB1 * K + cS;
    unsigned short* lA0 = sA + (w * 32) * 32 + L * 8;   // wave-uniform base + lane*16B
    unsigned short* lA1 = lA0 + 16 * 32;
    unsigned short* lB0 = sB + (w * 32) * 32 + L * 8;
    unsigned short* lB1 = lB0 + 16 * 32;

    int mw = (w >> 1) * 64, nw = (w & 1) * 64;
    const unsigned short* fA = sA + (mw + (L & 15)) * 32 + (L >> 4) * 8;
    const unsigned short* fB = sB + (nw + (L & 15)) * 32 + (L >> 4) * 8;

    f32x4 acc[4][4];
#pragma unroll
    for (int mi = 0; mi < 4; mi++)
#pragma unroll
        for (int ni = 0; ni < 4; ni++) acc[mi][ni] = (f32x4){0.f, 0.f, 0.f, 0.f};

    for (int kt = 0; kt < K; kt += 32) {
        gload16(gA0, lA0); gload16(gA1, lA1);
        gload16(gB0, lB0); gload16(gB1, lB1);
        gA0 += 32; gA1 += 32; gB0 += 32; gB1 += 32;
        __syncthreads();
        bf16x8 af[4], bf[4];
#pragma unroll
        for (int i = 0; i < 4; i++) {
            af[i] = *(const bf16x8*)(fA + i * 16 * 32);
            bf[i] = *(const bf16x8*)(fB + i * 16 * 32);
        }
#pragma unroll
        for (int mi = 0; mi < 4; mi++)
#pragma unroll
            for (int ni = 0; ni < 4; ni++)
                acc[mi][ni] = __builtin_amdgcn_mfma_f32_16x16x32_bf16(
                    af[mi], bf[ni], acc[mi][ni], 0, 0, 0);
        __syncthreads();
    }
    int rb = (L >> 4) * 4, cb = L & 15;
#pragma unroll
    for (int mi = 0; mi < 4; mi++)
#pragma unroll
        for (int ni = 0; ni < 4; ni++) {
            long c = n0 + nw + ni * 16 + cb;
            if (c >= nvalid) continue;
#pragma unroll
            for (int rg = 0; rg < 4; rg++) {
                long r = m0 + mw + mi * 16 + rb + rg;
                float v = acc[mi][ni][rg];
                if (EPI == 0) Cb[r * ldc + c] = f2b(v);
                else          Cf[r * ldc + c] = v + Res[r * ldc + c];
            }
        }
}

// ======= kernel 4: depthwise causal conv(4) + bias + silu over xBC ==========
// reads zx (bf16, stride 8384) cols [4096, 8320), writes xbc (4096 x 4224) bf16
__global__ __launch_bounds__(128) void k_conv(
    const unsigned short* __restrict__ zx, const float* __restrict__ cw,
    const float* __restrict__ cb, unsigned short* __restrict__ xbc)
{
    int c = blockIdx.x * 128 + threadIdx.x;   // 0..4223
    int b = blockIdx.z;
    int l0 = blockIdx.y * 64;
    float w0 = cw[c * 4 + 0], w1 = cw[c * 4 + 1];
    float w2 = cw[c * 4 + 2], w3 = cw[c * 4 + 3];
    float bias = cb[c];
    const unsigned short* src = zx + ((long)b * 2048) * 8384 + 4096 + c;
    float xm3 = (l0 >= 3) ? b2f(src[(long)(l0 - 3) * 8384]) : 0.f;
    float xm2 = (l0 >= 2) ? b2f(src[(long)(l0 - 2) * 8384]) : 0.f;
    float xm1 = (l0 >= 1) ? b2f(src[(long)(l0 - 1) * 8384]) : 0.f;
    const unsigned short* s2 = src + (long)l0 * 8384;
    unsigned short* dst = xbc + ((long)(b * 2048 + l0)) * 4224 + c;
#pragma unroll 8
    for (int i = 0; i < 64; i++) {
        float xl = b2f(*s2); s2 += 8384;
        float a = xm3 * w0 + xm2 * w1 + xm1 * w2 + xl * w3 + bias;
        a = a / (1.f + expf(-a));      // silu
        *dst = f2b(a); dst += 4224;
        xm3 = xm2; xm2 = xm1; xm1 = xl;
    }
}

// ================== kernel 5: sequential SSM scan ===========================
// grid 128 = (b,h). 512 threads: thread owns p=t>>3 (headdim), 8 states n.
// chunked: T=32 steps staged in LDS. y written into zx cols [4096,8192).
__global__ __launch_bounds__(512) void k_scan(
    const unsigned short* __restrict__ xbc, const unsigned short* __restrict__ zxdt,
    const float* __restrict__ dt_bias, const float* __restrict__ A_log,
    const float* __restrict__ Dv, unsigned short* __restrict__ yout)
{
    int bh = blockIdx.x; int b = bh >> 6, h = bh & 63;
    int t = threadIdx.x;
    __shared__ __align__(16) float sx[32 * 64], sB[32 * 64], sC[32 * 64], sy[32 * 64];
    __shared__ float sdt[32], sdA[32];
    float st[8];
#pragma unroll
    for (int i = 0; i < 8; i++) st[i] = 0.f;
    int p = t >> 3, q = t & 7, nb = q * 8;
    float Ah = expf(A_log[h]);
    float dtb = dt_bias[h];
    float Dh = Dv[h];
    const unsigned short* xrow = xbc + (long)b * 2048 * 4224;

    for (int l0 = 0; l0 < 2048; l0 += 32) {
        // ---- stage chunk into LDS (coalesced 64-wide runs) ----
#pragma unroll
        for (int i = 0; i < 12; i++) {
            int idx = i * 512 + t;            // 0..6143
            int s = idx / 192; int r = idx - s * 192;
            int seg = r >> 6, e = r & 63;
            const unsigned short* base = xrow + (long)(l0 + s) * 4224;
            if (seg == 0)      sx[s * 64 + e] = b2f(base[(h << 6) + e]);
            else if (seg == 1) sB[s * 64 + e] = b2f(base[4096 + e]);
            else               sC[s * 64 + e] = b2f(base[4160 + e]);
        }
        if (t < 32) {
            float raw = b2f(zxdt[((long)(b * 2048 + l0 + t)) * 8384 + 8320 + h]) + dtb;
            float dtv = (raw > 20.f) ? raw : log1pf(expf(raw));
            sdt[t] = dtv;
            sdA[t] = expf(-dtv * Ah);
        }
        __syncthreads();
        // ---- 32 sequential steps from LDS ----
#pragma unroll 4
        for (int s = 0; s < 32; s++) {
            float dA = sdA[s], dtv = sdt[s];
            float xp = sx[s * 64 + p];
            float coef = dtv * xp;
            float4 B0 = *(const float4*)(sB + s * 64 + nb);
            float4 B1 = *(const float4*)(sB + s * 64 + nb + 4);
            float4 C0 = *(const float4*)(sC + s * 64 + nb);
            float4 C1 = *(const float4*)(sC + s * 64 + nb + 4);
            float part;
            st[0] = st[0] * dA + coef * B0.x; part  = st[0] * C0.x;
            st[1] = st[1] * dA + coef * B0.y; part += st[1] * C0.y;
            st[2] = st[2] * dA + coef * B0.z; part += st[2] * C0.z;
            st[3] = st[3] * dA + coef * B0.w; part += st[3] * C0.w;
            st[4] = st[4] * dA + coef * B1.x; part += st[4] * C1.x;
            st[5] = st[5] * dA + coef * B1.y; part += st[5] * C1.y;
            st[6] = st[6] * dA + coef * B1.z; part += st[6] * C1.z;
            st[7] = st[7] * dA + coef * B1.w; part += st[7] * C1.w;
            part += __shfl_xor(part, 1);
            part += __shfl_xor(part, 2);
            part += __shfl_xor(part, 4);
            if (q == 0) sy[s * 64 + p] = part + Dh * xp;
        }
        __syncthreads();
        // ---- write y chunk (bf16) ----
#pragma unroll
        for (int i = 0; i < 4; i++) {
            int idx = i * 512 + t; int s = idx >> 6; int pp = idx & 63;
            yout[((long)(b * 2048 + l0 + s)) * 8384 + 4096 + (h << 6) + pp] =
                f2b(sy[s * 64 + pp]);
        }
    }
}

// ====== kernel 6: gated RMSNorm: y2 = rmsnorm(y * silu(z)) * norm_w (bf16) ==
__global__ __launch_bounds__(256) void k_gatenorm(
    const unsigned short* __restrict__ zx, const float* __restrict__ nw,
    unsigned short* __restrict__ y2)
{
    int row = blockIdx.x, t = threadIdx.x;
    const unsigned short* zr = zx + (long)row * 8384;
    float v[16]; float ss = 0.f;
#pragma unroll
    for (int i = 0; i < 16; i++) {
        int c = t + i * 256;
        float z = b2f(zr[c]);
        float y = b2f(zr[4096 + c]);
        float g = y * (z / (1.f + expf(-z)));
        v[i] = g; ss += g * g;
    }
#pragma unroll
    for (int o = 32; o > 0; o >>= 1) ss += __shfl_down(ss, o);
    __shared__ float red[4];
    if ((t & 63) == 0) red[t >> 6] = ss;
    __syncthreads();
    float tot = red[0] + red[1] + red[2] + red[3];
    float scale = rsqrtf(tot * (1.0f / 4096.0f) + 1e-5f);
#pragma unroll
    for (int i = 0; i < 16; i++) {
        int c = t + i * 256;
        y2[(long)row * 4096 + c] = f2b(v[i] * scale * nw[c]);
    }
}

// ============================= launcher =====================================
extern "C" void kernel_launch(void* const* d_in, const int* in_sizes, int n_in,
                              void* d_out, int out_size, void* d_ws, size_t ws_size,
                              hipStream_t stream)
{
    const float* h    = (const float*)d_in[0]; // (2,2048,2048)
    const float* rmsw = (const float*)d_in[1]; // (2048)
    const float* w1   = (const float*)d_in[2]; // (8384,2048)
    const float* cw   = (const float*)d_in[3]; // (4224,4)
    const float* cbp  = (const float*)d_in[4]; // (4224)
    const float* dtb  = (const float*)d_in[5]; // (64)
    const float* alog = (const float*)d_in[6]; // (64)
    const float* Dv   = (const float*)d_in[7]; // (64)
    const float* nw   = (const float*)d_in[8]; // (4096)
    const float* w2   = (const float*)d_in[9]; // (2048,4096)

    char* ws = (char*)d_ws;
    // ws layout (peak ~120.1 MB):
    //   [0, 68681728): zx bf16 4096x8384 (scan writes y into cols 4096..8192)
    //   [68681728, +34340864): w1b bf16 8384x2048  (dead after GEMM1)
    //       reused after conv: xbc bf16 4096x4224 (34603008 B, spills into u region)
    //       reused after gatenorm: y2 bf16 4096x4096
    //   [103022592, +16777216): u bf16 4096x2048 (dead after GEMM1)
    //   [103284736, +16777216): w2b bf16 2048x4096 (written after GEMM1)
    unsigned short* zx  = (unsigned short*)ws;
    unsigned short* w1b = (unsigned short*)(ws + 68681728L);
    unsigned short* xbc = (unsigned short*)(ws + 68681728L);
    unsigned short* y2  = (unsigned short*)(ws + 68681728L);
    unsigned short* u   = (unsigned short*)(ws + 103022592L);
    unsigned short* w2b = (unsigned short*)(ws + 103284736L);
    float* outp = (float*)d_out;

    k_rmsnorm_in<<<4096, 256, 0, stream>>>(h, rmsw, u);
    k_cvt<<<8384, 256, 0, stream>>>(w1, w1b);   // 8384*2048 elems
    // zx = u @ w1b^T : M=4096, N=8384 (66 tiles, clamped), K=2048
    k_gemm_bt<0><<<dim3(66, 32), 256, 0, stream>>>(u, w1b, 2048, 8384, zx, nullptr, 8384, nullptr);
    k_conv<<<dim3(33, 32, 2), 128, 0, stream>>>(zx, cw, cbp, xbc);
    k_cvt<<<4096, 256, 0, stream>>>(w2, w2b);   // 2048*4096 elems (after GEMM1: overlaps dead u)
    k_scan<<<128, 512, 0, stream>>>(xbc, zx, dtb, alog, Dv, zx);
    k_gatenorm<<<4096, 256, 0, stream>>>(zx, nw, y2);
    // out = y2 @ w2b^T + residual : M=4096, N=2048, K=4096, fp32 out
    k_gemm_bt<1><<<dim3(16, 32), 256, 0, stream>>>(y2, w2b, 4096, 2048, nullptr, outp, 2048, h);
}

// Round 5
// 853.984 us; speedup vs baseline: 1.4607x; 1.4607x over previous
//
#include <hip/hip_runtime.h>
#include <stdint.h>

#define DEV static __device__ __forceinline__

typedef __attribute__((ext_vector_type(8))) __bf16 bf16x8;
typedef __attribute__((ext_vector_type(4))) float f32x4;

// ---------- bf16 helpers ----------
DEV float b2f(unsigned short u) {
    union { unsigned int i; float f; } v; v.i = ((unsigned int)u) << 16; return v.f;
}
DEV unsigned short f2b(float f) {
    unsigned int u = __builtin_bit_cast(unsigned int, f);
    unsigned int r = (u + 0x7FFFu + ((u >> 16) & 1u)) >> 16;  // RNE
    return (unsigned short)r;
}

// ---------- async global->LDS, 16B per lane ----------
DEV void gload16(const void* g, void* l) {
    __builtin_amdgcn_global_load_lds(
        (const __attribute__((address_space(1))) void*)g,
        (__attribute__((address_space(3))) void*)l, 16, 0, 0);
}

// ============ kernel 0: fp32 -> bf16 copy (n multiple of 2048) ==============
__global__ __launch_bounds__(256) void k_cvt(
    const float* __restrict__ src, unsigned short* __restrict__ dst)
{
    long i = ((long)blockIdx.x * 256 + threadIdx.x) * 8;
    float4 a = *(const float4*)(src + i);
    float4 b = *(const float4*)(src + i + 4);
    union { uint4 v; unsigned short s[8]; } o;
    o.s[0] = f2b(a.x); o.s[1] = f2b(a.y); o.s[2] = f2b(a.z); o.s[3] = f2b(a.w);
    o.s[4] = f2b(b.x); o.s[5] = f2b(b.y); o.s[6] = f2b(b.z); o.s[7] = f2b(b.w);
    *(uint4*)(dst + i) = o.v;
}

// ================== kernel 1: RMSNorm of hidden -> u (bf16) =================
__global__ __launch_bounds__(256) void k_rmsnorm_in(
    const float* __restrict__ h, const float* __restrict__ w,
    unsigned short* __restrict__ u)
{
    int row = blockIdx.x, t = threadIdx.x;
    const float* hp = h + (long)row * 2048 + t * 8;
    float4 a = *(const float4*)hp;
    float4 b = *(const float4*)(hp + 4);
    float x[8] = {a.x, a.y, a.z, a.w, b.x, b.y, b.z, b.w};
    float ss = 0.f;
#pragma unroll
    for (int i = 0; i < 8; i++) ss += x[i] * x[i];
#pragma unroll
    for (int o = 32; o > 0; o >>= 1) ss += __shfl_down(ss, o);
    __shared__ float red[4];
    if ((t & 63) == 0) red[t >> 6] = ss;
    __syncthreads();
    float tot = red[0] + red[1] + red[2] + red[3];
    float scale = rsqrtf(tot * (1.0f / 2048.0f) + 1e-5f);
    float4 wa = *(const float4*)(w + t * 8);
    float4 wb = *(const float4*)(w + t * 8 + 4);
    float wv[8] = {wa.x, wa.y, wa.z, wa.w, wb.x, wb.y, wb.z, wb.w};
    union { uint4 v; unsigned short s[8]; } ow;
#pragma unroll
    for (int i = 0; i < 8; i++) ow.s[i] = f2b(x[i] * scale * wv[i]);
    *(uint4*)(u + (long)row * 2048 + t * 8) = ow.v;
}

// ================== GEMM: C[MxN] = A[MxK] * B[NxK]^T (bf16 in, fp32 acc) ====
// m97 structure: 128x128 tile, BK=32, 4 waves (2x2), 16x16x32 MFMA, 4x4 frags.
// EPI 0: store bf16 to Cb.  EPI 1: store fp32 (acc + fp32 Res) to Cf.
template <int EPI>
__global__ __launch_bounds__(256) void k_gemm_bt(
    const unsigned short* __restrict__ A, const unsigned short* __restrict__ Bm,
    int K, int nvalid, unsigned short* __restrict__ Cb, float* __restrict__ Cf,
    int ldc, const float* __restrict__ Res)
{
    __shared__ __align__(16) unsigned short sA[128 * 32];
    __shared__ __align__(16) unsigned short sB[128 * 32];
    int t = threadIdx.x;
    int w = t >> 6, L = t & 63;
    long m0 = (long)blockIdx.y * 128, n0 = (long)blockIdx.x * 128;

    int rS = w * 32 + (L >> 2);
    int cS = (L & 3) * 8;
    long rB0 = n0 + rS;       if (rB0 >= nvalid) rB0 = nvalid - 1;
    long rB1 = n0 + rS + 16;  if (rB1 >= nvalid) rB1 = nvalid - 1;
    const unsigned short* gA0 = A + (m0 + rS) * K + cS;
    const unsigned short* gA1 = gA0 + 16L * K;
    const unsigned short* gB0 = Bm + rB0 * K + cS;
    const unsigned short* gB1 = Bm + rB1 * K + cS;
    unsigned short* lA0 = sA + (w * 32) * 32 + L * 8;
    unsigned short* lA1 = lA0 + 16 * 32;
    unsigned short* lB0 = sB + (w * 32) * 32 + L * 8;
    unsigned short* lB1 = lB0 + 16 * 32;

    int mw = (w >> 1) * 64, nw = (w & 1) * 64;
    const unsigned short* fA = sA + (mw + (L & 15)) * 32 + (L >> 4) * 8;
    const unsigned short* fB = sB + (nw + (L & 15)) * 32 + (L >> 4) * 8;

    f32x4 acc[4][4];
#pragma unroll
    for (int mi = 0; mi < 4; mi++)
#pragma unroll
        for (int ni = 0; ni < 4; ni++) acc[mi][ni] = (f32x4){0.f, 0.f, 0.f, 0.f};

    for (int kt = 0; kt < K; kt += 32) {
        gload16(gA0, lA0); gload16(gA1, lA1);
        gload16(gB0, lB0); gload16(gB1, lB1);
        gA0 += 32; gA1 += 32; gB0 += 32; gB1 += 32;
        __syncthreads();
        bf16x8 af[4], bf[4];
#pragma unroll
        for (int i = 0; i < 4; i++) {
            af[i] = *(const bf16x8*)(fA + i * 16 * 32);
            bf[i] = *(const bf16x8*)(fB + i * 16 * 32);
        }
#pragma unroll
        for (int mi = 0; mi < 4; mi++)
#pragma unroll
            for (int ni = 0; ni < 4; ni++)
                acc[mi][ni] = __builtin_amdgcn_mfma_f32_16x16x32_bf16(
                    af[mi], bf[ni], acc[mi][ni], 0, 0, 0);
        __syncthreads();
    }
    int rb = (L >> 4) * 4, cb = L & 15;
#pragma unroll
    for (int mi = 0; mi < 4; mi++)
#pragma unroll
        for (int ni = 0; ni < 4; ni++) {
            long c = n0 + nw + ni * 16 + cb;
            if (c >= nvalid) continue;
#pragma unroll
            for (int rg = 0; rg < 4; rg++) {
                long r = m0 + mw + mi * 16 + rb + rg;
                float v = acc[mi][ni][rg];
                if (EPI == 0) Cb[r * ldc + c] = f2b(v);
                else          Cf[r * ldc + c] = v + Res[r * ldc + c];
            }
        }
}

// ======= kernel 4: depthwise causal conv(4) + bias + silu over xBC ==========
__global__ __launch_bounds__(128) void k_conv(
    const unsigned short* __restrict__ zx, const float* __restrict__ cw,
    const float* __restrict__ cb, unsigned short* __restrict__ xbc)
{
    int c = blockIdx.x * 128 + threadIdx.x;   // 0..4223
    int b = blockIdx.z;
    int l0 = blockIdx.y * 64;
    float w0 = cw[c * 4 + 0], w1 = cw[c * 4 + 1];
    float w2 = cw[c * 4 + 2], w3 = cw[c * 4 + 3];
    float bias = cb[c];
    const unsigned short* src = zx + ((long)b * 2048) * 8384 + 4096 + c;
    float xm3 = (l0 >= 3) ? b2f(src[(long)(l0 - 3) * 8384]) : 0.f;
    float xm2 = (l0 >= 2) ? b2f(src[(long)(l0 - 2) * 8384]) : 0.f;
    float xm1 = (l0 >= 1) ? b2f(src[(long)(l0 - 1) * 8384]) : 0.f;
    const unsigned short* s2 = src + (long)l0 * 8384;
    unsigned short* dst = xbc + ((long)(b * 2048 + l0)) * 4224 + c;
#pragma unroll 8
    for (int i = 0; i < 64; i++) {
        float xl = b2f(*s2); s2 += 8384;
        float a = xm3 * w0 + xm2 * w1 + xm1 * w2 + xl * w3 + bias;
        a = a / (1.f + expf(-a));      // silu
        *dst = f2b(a); dst += 4224;
        xm3 = xm2; xm2 = xm1; xm1 = xl;
    }
}

// ============ kernel 5a: per-chunk state contribution (pass 1) ==============
// grid 1024 = (bh, 8 chunks of 256 steps). block 512: thread owns p=t>>3, 8 n's.
// Computes S_c (state contribution starting from 0) and dAtot_c.
__global__ __launch_bounds__(512) void k_chunk_state(
    const unsigned short* __restrict__ xbc, const unsigned short* __restrict__ zxdt,
    const float* __restrict__ dt_bias, const float* __restrict__ A_log,
    unsigned short* __restrict__ Sbuf, float* __restrict__ dAtot)
{
    int blk = blockIdx.x;
    int c = blk & 7, bh = blk >> 3;
    int b = bh >> 6, h = bh & 63;
    int t = threadIdx.x;
    __shared__ __align__(16) float sx[32 * 64], sB[32 * 64];
    __shared__ float sdt[32], sdA[32];
    float st[8];
#pragma unroll
    for (int i = 0; i < 8; i++) st[i] = 0.f;
    int p = t >> 3, q = t & 7, nb = q * 8;
    float Ah = expf(A_log[h]);
    float dtb = dt_bias[h];
    const unsigned short* xrow = xbc + (long)b * 2048 * 4224;
    float dtsum = 0.f;

    for (int sub = 0; sub < 8; sub++) {
        int l0 = c * 256 + sub * 32;
#pragma unroll
        for (int i = 0; i < 8; i++) {
            int idx = i * 512 + t;            // 0..4095
            int s = idx >> 7, r = idx & 127;
            int seg = r >> 6, e = r & 63;
            const unsigned short* base = xrow + (long)(l0 + s) * 4224;
            if (seg == 0) sx[s * 64 + e] = b2f(base[(h << 6) + e]);
            else          sB[s * 64 + e] = b2f(base[4096 + e]);
        }
        if (t < 32) {
            float raw = b2f(zxdt[((long)(b * 2048 + l0 + t)) * 8384 + 8320 + h]) + dtb;
            float dtv = (raw > 20.f) ? raw : log1pf(expf(raw));
            sdt[t] = dtv;
            sdA[t] = expf(-dtv * Ah);
        }
        __syncthreads();
#pragma unroll 4
        for (int s = 0; s < 32; s++) {
            float dA = sdA[s];
            float coef = sdt[s] * sx[s * 64 + p];
            float4 B0 = *(const float4*)(sB + s * 64 + nb);
            float4 B1 = *(const float4*)(sB + s * 64 + nb + 4);
            st[0] = st[0] * dA + coef * B0.x;
            st[1] = st[1] * dA + coef * B0.y;
            st[2] = st[2] * dA + coef * B0.z;
            st[3] = st[3] * dA + coef * B0.w;
            st[4] = st[4] * dA + coef * B1.x;
            st[5] = st[5] * dA + coef * B1.y;
            st[6] = st[6] * dA + coef * B1.z;
            st[7] = st[7] * dA + coef * B1.w;
        }
#pragma unroll 8
        for (int s = 0; s < 32; s++) dtsum += sdt[s];   // wave-uniform broadcast reads
        __syncthreads();
    }
    union { uint4 v; unsigned short s[8]; } o;
#pragma unroll
    for (int j = 0; j < 8; j++) o.s[j] = f2b(st[j]);
    *(uint4*)(Sbuf + (long)blk * 4096 + p * 64 + nb) = o.v;
    if (t == 0) dAtot[blk] = expf(-Ah * dtsum);
}

// ============ kernel 5b: scan within chunk from combined state (pass 2) =====
// grid 1024. Combines H = sum_{j<c} (prod dAtot) S_j locally, then scans its
// 256 steps writing y into zx cols [4096,8192).
__global__ __launch_bounds__(512) void k_scan_chunk(
    const unsigned short* __restrict__ xbc, const unsigned short* __restrict__ zxdt,
    const float* __restrict__ dt_bias, const float* __restrict__ A_log,
    const float* __restrict__ Dv,
    const unsigned short* __restrict__ Sbuf, const float* __restrict__ dAtot,
    unsigned short* __restrict__ yout)
{
    int blk = blockIdx.x;
    int c = blk & 7, bh = blk >> 3;
    int b = bh >> 6, h = bh & 63;
    int t = threadIdx.x;
    __shared__ __align__(16) float sx[32 * 64], sB[32 * 64], sC[32 * 64], sy[32 * 64];
    __shared__ float sdt[32], sdA[32];
    int p = t >> 3, q = t & 7, nb = q * 8;
    float Ah = expf(A_log[h]);
    float dtb = dt_bias[h];
    float Dh = Dv[h];
    const unsigned short* xrow = xbc + (long)b * 2048 * 4224;

    // ---- combine initial state from prior chunks ----
    float st[8];
#pragma unroll
    for (int i = 0; i < 8; i++) st[i] = 0.f;
    int sb = bh * 8;
    for (int j = 0; j < c; j++) {
        float d = dAtot[sb + j];
        union { uint4 v; unsigned short s[8]; } sv;
        sv.v = *(const uint4*)(Sbuf + (long)(sb + j) * 4096 + p * 64 + nb);
#pragma unroll
        for (int k = 0; k < 8; k++) st[k] = st[k] * d + b2f(sv.s[k]);
    }

    for (int sub = 0; sub < 8; sub++) {
        int l0 = c * 256 + sub * 32;
#pragma unroll
        for (int i = 0; i < 12; i++) {
            int idx = i * 512 + t;            // 0..6143
            int s = idx / 192; int r = idx - s * 192;
            int seg = r >> 6, e = r & 63;
            const unsigned short* base = xrow + (long)(l0 + s) * 4224;
            if (seg == 0)      sx[s * 64 + e] = b2f(base[(h << 6) + e]);
            else if (seg == 1) sB[s * 64 + e] = b2f(base[4096 + e]);
            else               sC[s * 64 + e] = b2f(base[4160 + e]);
        }
        if (t < 32) {
            float raw = b2f(zxdt[((long)(b * 2048 + l0 + t)) * 8384 + 8320 + h]) + dtb;
            float dtv = (raw > 20.f) ? raw : log1pf(expf(raw));
            sdt[t] = dtv;
            sdA[t] = expf(-dtv * Ah);
        }
        __syncthreads();
#pragma unroll 4
        for (int s = 0; s < 32; s++) {
            float dA = sdA[s], dtv = sdt[s];
            float xp = sx[s * 64 + p];
            float coef = dtv * xp;
            float4 B0 = *(const float4*)(sB + s * 64 + nb);
            float4 B1 = *(const float4*)(sB + s * 64 + nb + 4);
            float4 C0 = *(const float4*)(sC + s * 64 + nb);
            float4 C1 = *(const float4*)(sC + s * 64 + nb + 4);
            float part;
            st[0] = st[0] * dA + coef * B0.x; part  = st[0] * C0.x;
            st[1] = st[1] * dA + coef * B0.y; part += st[1] * C0.y;
            st[2] = st[2] * dA + coef * B0.z; part += st[2] * C0.z;
            st[3] = st[3] * dA + coef * B0.w; part += st[3] * C0.w;
            st[4] = st[4] * dA + coef * B1.x; part += st[4] * C1.x;
            st[5] = st[5] * dA + coef * B1.y; part += st[5] * C1.y;
            st[6] = st[6] * dA + coef * B1.z; part += st[6] * C1.z;
            st[7] = st[7] * dA + coef * B1.w; part += st[7] * C1.w;
            part += __shfl_xor(part, 1);
            part += __shfl_xor(part, 2);
            part += __shfl_xor(part, 4);
            if (q == 0) sy[s * 64 + p] = part + Dh * xp;
        }
        __syncthreads();
#pragma unroll
        for (int i = 0; i < 4; i++) {
            int idx = i * 512 + t; int s = idx >> 6; int pp = idx & 63;
            yout[((long)(b * 2048 + l0 + s)) * 8384 + 4096 + (h << 6) + pp] =
                f2b(sy[s * 64 + pp]);
        }
        __syncthreads();
    }
}

// ====== kernel 6: gated RMSNorm: y2 = rmsnorm(y * silu(z)) * norm_w (bf16) ==
__global__ __launch_bounds__(256) void k_gatenorm(
    const unsigned short* __restrict__ zx, const float* __restrict__ nw,
    unsigned short* __restrict__ y2)
{
    int row = blockIdx.x, t = threadIdx.x;
    const unsigned short* zr = zx + (long)row * 8384;
    float v[16]; float ss = 0.f;
#pragma unroll
    for (int i = 0; i < 16; i++) {
        int c = t + i * 256;
        float z = b2f(zr[c]);
        float y = b2f(zr[4096 + c]);
        float g = y * (z / (1.f + expf(-z)));
        v[i] = g; ss += g * g;
    }
#pragma unroll
    for (int o = 32; o > 0; o >>= 1) ss += __shfl_down(ss, o);
    __shared__ float red[4];
    if ((t & 63) == 0) red[t >> 6] = ss;
    __syncthreads();
    float tot = red[0] + red[1] + red[2] + red[3];
    float scale = rsqrtf(tot * (1.0f / 4096.0f) + 1e-5f);
#pragma unroll
    for (int i = 0; i < 16; i++) {
        int c = t + i * 256;
        y2[(long)row * 4096 + c] = f2b(v[i] * scale * nw[c]);
    }
}

// ============================= launcher =====================================
extern "C" void kernel_launch(void* const* d_in, const int* in_sizes, int n_in,
                              void* d_out, int out_size, void* d_ws, size_t ws_size,
                              hipStream_t stream)
{
    const float* h    = (const float*)d_in[0]; // (2,2048,2048)
    const float* rmsw = (const float*)d_in[1]; // (2048)
    const float* w1   = (const float*)d_in[2]; // (8384,2048)
    const float* cw   = (const float*)d_in[3]; // (4224,4)
    const float* cbp  = (const float*)d_in[4]; // (4224)
    const float* dtb  = (const float*)d_in[5]; // (64)
    const float* alog = (const float*)d_in[6]; // (64)
    const float* Dv   = (const float*)d_in[7]; // (64)
    const float* nw   = (const float*)d_in[8]; // (4096)
    const float* w2   = (const float*)d_in[9]; // (2048,4096)

    char* ws = (char*)d_ws;
    // ws layout (peak 120,061,952 B — proven in R3):
    //   [0, 68681728): zx bf16 4096x8384 (scan writes y into cols 4096..8192)
    //   [68681728, 103284736): w1b bf16 (dead after GEMM1)
    //       -> reused: xbc bf16 4096x4224 (NOTE: ends exactly at 103284736)
    //       -> reused after scan: y2 bf16 4096x4096
    //   [103284736, 111673344): Sbuf bf16 1024x4096  (NO overlap with xbc!)
    //   [111673344, +4096):     dAt fp32 1024
    //   [103284736, 120061952): w2b bf16 — cvt AFTER scan (Sbuf/dAt dead)
    //   u bf16 4096x2048 at [103022592, 119799808)?? NO — u must not overlap
    //   xbc tail; u lives only before GEMM1 while xbc doesn't exist yet, and
    //   w1b [68681728,103284736) is separate. Keep u at 103284736 (16.77 MB).
    unsigned short* zx    = (unsigned short*)ws;
    unsigned short* w1b   = (unsigned short*)(ws + 68681728L);
    unsigned short* xbc   = (unsigned short*)(ws + 68681728L);
    unsigned short* y2    = (unsigned short*)(ws + 68681728L);
    unsigned short* u     = (unsigned short*)(ws + 103284736L);
    unsigned short* Sbuf  = (unsigned short*)(ws + 103284736L);
    float*          dAt   = (float*)(ws + 111673344L);
    unsigned short* w2b   = (unsigned short*)(ws + 103284736L);
    float* outp = (float*)d_out;

    k_rmsnorm_in<<<4096, 256, 0, stream>>>(h, rmsw, u);
    k_cvt<<<8384, 256, 0, stream>>>(w1, w1b);
    // zx = u @ w1b^T : M=4096, N=8384 (66 tiles, clamped), K=2048
    k_gemm_bt<0><<<dim3(66, 32), 256, 0, stream>>>(u, w1b, 2048, 8384, zx, nullptr, 8384, nullptr);
    k_conv<<<dim3(33, 32, 2), 128, 0, stream>>>(zx, cw, cbp, xbc);
    k_chunk_state<<<1024, 512, 0, stream>>>(xbc, zx, dtb, alog, Sbuf, dAt);
    k_scan_chunk<<<1024, 512, 0, stream>>>(xbc, zx, dtb, alog, Dv, Sbuf, dAt, zx);
    k_gatenorm<<<4096, 256, 0, stream>>>(zx, nw, y2);
    k_cvt<<<4096, 256, 0, stream>>>(w2, w2b);
    // out = y2 @ w2b^T + residual : M=4096, N=2048, K=4096, fp32 out
    k_gemm_bt<1><<<dim3(16, 32), 256, 0, stream>>>(y2, w2b, 4096, 2048, nullptr, outp, 2048, h);
}

// Round 6
// 600.021 us; speedup vs baseline: 2.0790x; 1.4233x over previous
//
#include <hip/hip_runtime.h>
#include <stdint.h>

#define DEV static __device__ __forceinline__

typedef __attribute__((ext_vector_type(8))) __bf16 bf16x8;
typedef __attribute__((ext_vector_type(4))) float f32x4;

// ---------- bf16 helpers ----------
DEV float b2f(unsigned short u) {
    union { unsigned int i; float f; } v; v.i = ((unsigned int)u) << 16; return v.f;
}
DEV unsigned short f2b(float f) {
    unsigned int u = __builtin_bit_cast(unsigned int, f);
    unsigned int r = (u + 0x7FFFu + ((u >> 16) & 1u)) >> 16;  // RNE
    return (unsigned short)r;
}
DEV f32x4 mfma16(bf16x8 a, bf16x8 b, f32x4 c) {
    return __builtin_amdgcn_mfma_f32_16x16x32_bf16(a, b, c, 0, 0, 0);
}

// ---------- async global->LDS, 16B per lane ----------
DEV void gload16(const void* g, void* l) {
    __builtin_amdgcn_global_load_lds(
        (const __attribute__((address_space(1))) void*)g,
        (__attribute__((address_space(3))) void*)l, 16, 0, 0);
}

// ============ kernel 0: fp32 -> bf16 copy (n multiple of 2048) ==============
__global__ __launch_bounds__(256) void k_cvt(
    const float* __restrict__ src, unsigned short* __restrict__ dst)
{
    long i = ((long)blockIdx.x * 256 + threadIdx.x) * 8;
    float4 a = *(const float4*)(src + i);
    float4 b = *(const float4*)(src + i + 4);
    union { uint4 v; unsigned short s[8]; } o;
    o.s[0] = f2b(a.x); o.s[1] = f2b(a.y); o.s[2] = f2b(a.z); o.s[3] = f2b(a.w);
    o.s[4] = f2b(b.x); o.s[5] = f2b(b.y); o.s[6] = f2b(b.z); o.s[7] = f2b(b.w);
    *(uint4*)(dst + i) = o.v;
}

// ================== kernel 1: RMSNorm of hidden -> u (bf16) =================
__global__ __launch_bounds__(256) void k_rmsnorm_in(
    const float* __restrict__ h, const float* __restrict__ w,
    unsigned short* __restrict__ u)
{
    int row = blockIdx.x, t = threadIdx.x;
    const float* hp = h + (long)row * 2048 + t * 8;
    float4 a = *(const float4*)hp;
    float4 b = *(const float4*)(hp + 4);
    float x[8] = {a.x, a.y, a.z, a.w, b.x, b.y, b.z, b.w};
    float ss = 0.f;
#pragma unroll
    for (int i = 0; i < 8; i++) ss += x[i] * x[i];
#pragma unroll
    for (int o = 32; o > 0; o >>= 1) ss += __shfl_down(ss, o);
    __shared__ float red[4];
    if ((t & 63) == 0) red[t >> 6] = ss;
    __syncthreads();
    float tot = red[0] + red[1] + red[2] + red[3];
    float scale = rsqrtf(tot * (1.0f / 2048.0f) + 1e-5f);
    float4 wa = *(const float4*)(w + t * 8);
    float4 wb = *(const float4*)(w + t * 8 + 4);
    float wv[8] = {wa.x, wa.y, wa.z, wa.w, wb.x, wb.y, wb.z, wb.w};
    union { uint4 v; unsigned short s[8]; } ow;
#pragma unroll
    for (int i = 0; i < 8; i++) ow.s[i] = f2b(x[i] * scale * wv[i]);
    *(uint4*)(u + (long)row * 2048 + t * 8) = ow.v;
}

// ================== GEMM: C[MxN] = A[MxK] * B[NxK]^T (bf16 in, fp32 acc) ====
template <int EPI>
__global__ __launch_bounds__(256) void k_gemm_bt(
    const unsigned short* __restrict__ A, const unsigned short* __restrict__ Bm,
    int K, int nvalid, unsigned short* __restrict__ Cb, float* __restrict__ Cf,
    int ldc, const float* __restrict__ Res)
{
    __shared__ __align__(16) unsigned short sA[128 * 32];
    __shared__ __align__(16) unsigned short sB[128 * 32];
    int t = threadIdx.x;
    int w = t >> 6, L = t & 63;
    long m0 = (long)blockIdx.y * 128, n0 = (long)blockIdx.x * 128;

    int rS = w * 32 + (L >> 2);
    int cS = (L & 3) * 8;
    long rB0 = n0 + rS;       if (rB0 >= nvalid) rB0 = nvalid - 1;
    long rB1 = n0 + rS + 16;  if (rB1 >= nvalid) rB1 = nvalid - 1;
    const unsigned short* gA0 = A + (m0 + rS) * K + cS;
    const unsigned short* gA1 = gA0 + 16L * K;
    const unsigned short* gB0 = Bm + rB0 * K + cS;
    const unsigned short* gB1 = Bm + rB1 * K + cS;
    unsigned short* lA0 = sA + (w * 32) * 32 + L * 8;
    unsigned short* lA1 = lA0 + 16 * 32;
    unsigned short* lB0 = sB + (w * 32) * 32 + L * 8;
    unsigned short* lB1 = lB0 + 16 * 32;

    int mw = (w >> 1) * 64, nw = (w & 1) * 64;
    const unsigned short* fA = sA + (mw + (L & 15)) * 32 + (L >> 4) * 8;
    const unsigned short* fB = sB + (nw + (L & 15)) * 32 + (L >> 4) * 8;

    f32x4 acc[4][4];
#pragma unroll
    for (int mi = 0; mi < 4; mi++)
#pragma unroll
        for (int ni = 0; ni < 4; ni++) acc[mi][ni] = (f32x4){0.f, 0.f, 0.f, 0.f};

    for (int kt = 0; kt < K; kt += 32) {
        gload16(gA0, lA0); gload16(gA1, lA1);
        gload16(gB0, lB0); gload16(gB1, lB1);
        gA0 += 32; gA1 += 32; gB0 += 32; gB1 += 32;
        __syncthreads();
        bf16x8 af[4], bf[4];
#pragma unroll
        for (int i = 0; i < 4; i++) {
            af[i] = *(const bf16x8*)(fA + i * 16 * 32);
            bf[i] = *(const bf16x8*)(fB + i * 16 * 32);
        }
#pragma unroll
        for (int mi = 0; mi < 4; mi++)
#pragma unroll
            for (int ni = 0; ni < 4; ni++)
                acc[mi][ni] = mfma16(af[mi], bf[ni], acc[mi][ni]);
        __syncthreads();
    }
    int rb = (L >> 4) * 4, cb = L & 15;
#pragma unroll
    for (int mi = 0; mi < 4; mi++)
#pragma unroll
        for (int ni = 0; ni < 4; ni++) {
            long c = n0 + nw + ni * 16 + cb;
            if (c >= nvalid) continue;
#pragma unroll
            for (int rg = 0; rg < 4; rg++) {
                long r = m0 + mw + mi * 16 + rb + rg;
                float v = acc[mi][ni][rg];
                if (EPI == 0) Cb[r * ldc + c] = f2b(v);
                else          Cf[r * ldc + c] = v + Res[r * ldc + c];
            }
        }
}

// ======= kernel 4: depthwise causal conv(4) + bias + silu over xBC ==========
__global__ __launch_bounds__(128) void k_conv(
    const unsigned short* __restrict__ zx, const float* __restrict__ cw,
    const float* __restrict__ cb, unsigned short* __restrict__ xbc)
{
    int c = blockIdx.x * 128 + threadIdx.x;   // 0..4223
    int b = blockIdx.z;
    int l0 = blockIdx.y * 64;
    float w0 = cw[c * 4 + 0], w1 = cw[c * 4 + 1];
    float w2 = cw[c * 4 + 2], w3 = cw[c * 4 + 3];
    float bias = cb[c];
    const unsigned short* src = zx + ((long)b * 2048) * 8384 + 4096 + c;
    float xm3 = (l0 >= 3) ? b2f(src[(long)(l0 - 3) * 8384]) : 0.f;
    float xm2 = (l0 >= 2) ? b2f(src[(long)(l0 - 2) * 8384]) : 0.f;
    float xm1 = (l0 >= 1) ? b2f(src[(long)(l0 - 1) * 8384]) : 0.f;
    const unsigned short* s2 = src + (long)l0 * 8384;
    unsigned short* dst = xbc + ((long)(b * 2048 + l0)) * 4224 + c;
#pragma unroll 8
    for (int i = 0; i < 64; i++) {
        float xl = b2f(*s2); s2 += 8384;
        float a = xm3 * w0 + xm2 * w1 + xm1 * w2 + xl * w3 + bias;
        a = a / (1.f + expf(-a));      // silu
        *dst = f2b(a); dst += 4224;
        xm3 = xm2; xm2 = xm1; xm1 = xl;
    }
}

// ============ kernel 5a: per-chunk state via MFMA (pass 1) ==================
// grid 1024 = (bh, 8 chunks of 256). block 256 (4 waves).
// Per 64-step sub-chunk: H = e_end*H + Xw^T @ B  (one 64x64x64 MFMA matmul).
__global__ __launch_bounds__(256) void k_chunk_state_mfma(
    const unsigned short* __restrict__ xbc, const unsigned short* __restrict__ zxdt,
    const float* __restrict__ dt_bias, const float* __restrict__ A_log,
    unsigned short* __restrict__ Sbuf, float* __restrict__ dAtot)
{
    int blk = blockIdx.x;
    int c = blk & 7, bh = blk >> 3;
    int b = bh >> 6, h = bh & 63;
    int tid = threadIdx.x;
    int w = tid >> 6, L = tid & 63;
    int quad = L >> 4, col = L & 15;
    int rowBlk = (w >> 1) * 32, colBlk = (w & 1) * 32;
    __shared__ __align__(16) unsigned short sXp[64 * 72];  // X^T (p,t)
    __shared__ __align__(16) unsigned short sBn[64 * 72];  // scaled B^T (n,t)
    __shared__ float sdt[64], sL[64];
    float Ah = expf(A_log[h]);
    float dtb = dt_bias[h];
    f32x4 acc[2][2];
#pragma unroll
    for (int ti = 0; ti < 2; ti++)
#pragma unroll
        for (int tj = 0; tj < 2; tj++) acc[ti][tj] = (f32x4){0.f, 0.f, 0.f, 0.f};
    float sumL = 0.f;

    for (int sub = 0; sub < 4; sub++) {
        int l0 = c * 256 + sub * 64;
        // stage X transposed -> (p,t)
        {
            int t = tid >> 2, pc = tid & 3;
            const unsigned short* gX = xbc + (long)(b * 2048 + l0 + t) * 4224 + h * 64 + pc * 16;
            union { uint4 v; unsigned short s[8]; } x0, x1;
            x0.v = *(const uint4*)gX; x1.v = *(const uint4*)(gX + 8);
#pragma unroll
            for (int j = 0; j < 8; j++) {
                sXp[(pc * 16 + j) * 72 + t] = x0.s[j];
                sXp[(pc * 16 + 8 + j) * 72 + t] = x1.s[j];
            }
        }
        // dt, cumulative log-decay (wave 0)
        if (tid < 64) {
            float raw = b2f(zxdt[((long)(b * 2048 + l0 + tid)) * 8384 + 8320 + h]) + dtb;
            float dtv = (raw > 20.f) ? raw : log1pf(expf(raw));
            float cum = dtv;
#pragma unroll
            for (int off = 1; off < 64; off <<= 1) {
                float v = __shfl_up(cum, off);
                if (tid >= off) cum += v;
            }
            sdt[tid] = dtv;
            sL[tid] = -Ah * cum;
        }
        __syncthreads();
        float Lend = sL[63];
        // stage B transposed & scaled: Bn[n][t] = B[t][n] * dt_t * exp(Lend - L_t)
        {
            int t = tid >> 2, nc = tid & 3;
            float wt = sdt[t] * __expf(Lend - sL[t]);
            const unsigned short* gB = xbc + (long)(b * 2048 + l0 + t) * 4224 + 4096 + nc * 16;
            union { uint4 v; unsigned short s[8]; } x0, x1;
            x0.v = *(const uint4*)gB; x1.v = *(const uint4*)(gB + 8);
#pragma unroll
            for (int j = 0; j < 8; j++) {
                sBn[(nc * 16 + j) * 72 + t] = f2b(b2f(x0.s[j]) * wt);
                sBn[(nc * 16 + 8 + j) * 72 + t] = f2b(b2f(x1.s[j]) * wt);
            }
        }
        __syncthreads();
        float e_end = __expf(Lend);
        sumL += Lend;
#pragma unroll
        for (int ti = 0; ti < 2; ti++)
#pragma unroll
            for (int tj = 0; tj < 2; tj++)
#pragma unroll
                for (int r = 0; r < 4; r++) acc[ti][tj][r] *= e_end;
#pragma unroll
        for (int kb = 0; kb < 2; kb++) {
            bf16x8 ax[2], bx[2];
#pragma unroll
            for (int ti = 0; ti < 2; ti++)
                ax[ti] = *(const bf16x8*)(sXp + (rowBlk + ti * 16 + col) * 72 + kb * 32 + quad * 8);
#pragma unroll
            for (int tj = 0; tj < 2; tj++)
                bx[tj] = *(const bf16x8*)(sBn + (colBlk + tj * 16 + col) * 72 + kb * 32 + quad * 8);
#pragma unroll
            for (int ti = 0; ti < 2; ti++)
#pragma unroll
                for (int tj = 0; tj < 2; tj++)
                    acc[ti][tj] = mfma16(ax[ti], bx[tj], acc[ti][tj]);
        }
        __syncthreads();
    }
#pragma unroll
    for (int ti = 0; ti < 2; ti++)
#pragma unroll
        for (int tj = 0; tj < 2; tj++)
#pragma unroll
            for (int r = 0; r < 4; r++) {
                int p = rowBlk + ti * 16 + quad * 4 + r;
                int n = colBlk + tj * 16 + col;
                Sbuf[(long)blk * 4096 + p * 64 + n] = f2b(acc[ti][tj][r]);
            }
    if (tid == 0) dAtot[blk] = __expf(sumL);
}

// ============ kernel 5b: SSD intra-chunk via MFMA (pass 2) ==================
// grid 1024. Combine prefix states, then per 64-step sub-chunk:
//   G = C@B^T ; M = mask(G)*dt*exp(Ls-Lt) ; Y = M@X + (es*C)@H^T ; H = e*H + Xw^T@B
__global__ __launch_bounds__(256) void k_scan_chunk_mfma(
    const unsigned short* __restrict__ xbc, const unsigned short* __restrict__ zxdt,
    const float* __restrict__ dt_bias, const float* __restrict__ A_log,
    const float* __restrict__ Dv,
    const unsigned short* __restrict__ Sbuf, const float* __restrict__ dAtot,
    unsigned short* __restrict__ yout)
{
    int blk = blockIdx.x;
    int c = blk & 7, bh = blk >> 3;
    int b = bh >> 6, h = bh & 63;
    int tid = threadIdx.x;
    int w = tid >> 6, L = tid & 63;
    int quad = L >> 4, col = L & 15;
    int rowBlk = (w >> 1) * 32, colBlk = (w & 1) * 32;
    __shared__ __align__(16) unsigned short sCm[64 * 72];    // C (s,n)
    __shared__ __align__(16) unsigned short sBtMs[64 * 72];  // B (t,n) -> reused as M (s,t)
    __shared__ __align__(16) unsigned short sXp[64 * 72];    // X^T (p,t)
    __shared__ __align__(16) unsigned short sBn[64 * 72];    // scaled B^T (n,t)
    __shared__ __align__(16) unsigned short sHb[64 * 72];    // H (p,n) bf16
    __shared__ float sdt[64], sL[64], sEs[64];
    float Ah = expf(A_log[h]);
    float dtb = dt_bias[h];
    float Dh = Dv[h];

    // ---- combine prefix chunk states into H accumulator (fragment layout) ----
    f32x4 acc_h[2][2];
#pragma unroll
    for (int ti = 0; ti < 2; ti++)
#pragma unroll
        for (int tj = 0; tj < 2; tj++) acc_h[ti][tj] = (f32x4){0.f, 0.f, 0.f, 0.f};
    int sb = bh * 8;
    for (int j = 0; j < c; j++) {
        float d = dAtot[sb + j];
        const unsigned short* Sp = Sbuf + (long)(sb + j) * 4096;
#pragma unroll
        for (int ti = 0; ti < 2; ti++)
#pragma unroll
            for (int tj = 0; tj < 2; tj++)
#pragma unroll
                for (int r = 0; r < 4; r++) {
                    int p = rowBlk + ti * 16 + quad * 4 + r;
                    int n = colBlk + tj * 16 + col;
                    acc_h[ti][tj][r] = acc_h[ti][tj][r] * d + b2f(Sp[p * 64 + n]);
                }
    }

    for (int sub = 0; sub < 4; sub++) {
        int l0 = c * 256 + sub * 64;
        // (a) stage C (s,n) and B (t,n), stride-72 rows
        {
            int row = tid >> 2, c4 = tid & 3;
            const unsigned short* gR = xbc + (long)(b * 2048 + l0 + row) * 4224;
            uint4 v0 = *(const uint4*)(gR + 4160 + c4 * 8);
            uint4 v1 = *(const uint4*)(gR + 4160 + (c4 + 4) * 8);
            *(uint4*)(sCm + row * 72 + c4 * 8) = v0;
            *(uint4*)(sCm + row * 72 + (c4 + 4) * 8) = v1;
            uint4 w0 = *(const uint4*)(gR + 4096 + c4 * 8);
            uint4 w1 = *(const uint4*)(gR + 4096 + (c4 + 4) * 8);
            *(uint4*)(sBtMs + row * 72 + c4 * 8) = w0;
            *(uint4*)(sBtMs + row * 72 + (c4 + 4) * 8) = w1;
        }
        // stage X transposed
        {
            int t = tid >> 2, pc = tid & 3;
            const unsigned short* gX = xbc + (long)(b * 2048 + l0 + t) * 4224 + h * 64 + pc * 16;
            union { uint4 v; unsigned short s[8]; } x0, x1;
            x0.v = *(const uint4*)gX; x1.v = *(const uint4*)(gX + 8);
#pragma unroll
            for (int j = 0; j < 8; j++) {
                sXp[(pc * 16 + j) * 72 + t] = x0.s[j];
                sXp[(pc * 16 + 8 + j) * 72 + t] = x1.s[j];
            }
        }
        // (b) dt / L / exp(L)
        if (tid < 64) {
            float raw = b2f(zxdt[((long)(b * 2048 + l0 + tid)) * 8384 + 8320 + h]) + dtb;
            float dtv = (raw > 20.f) ? raw : log1pf(expf(raw));
            float cum = dtv;
#pragma unroll
            for (int off = 1; off < 64; off <<= 1) {
                float v = __shfl_up(cum, off);
                if (tid >= off) cum += v;
            }
            sdt[tid] = dtv;
            float l = -Ah * cum;
            sL[tid] = l;
            sEs[tid] = __expf(l);
        }
        __syncthreads();
        float Lend = sL[63];
        // (c) stage scaled-transposed B; write H (bf16) for Ycross
        {
            int t = tid >> 2, nc = tid & 3;
            float wt = sdt[t] * __expf(Lend - sL[t]);
            const unsigned short* gB = xbc + (long)(b * 2048 + l0 + t) * 4224 + 4096 + nc * 16;
            union { uint4 v; unsigned short s[8]; } x0, x1;
            x0.v = *(const uint4*)gB; x1.v = *(const uint4*)(gB + 8);
#pragma unroll
            for (int j = 0; j < 8; j++) {
                sBn[(nc * 16 + j) * 72 + t] = f2b(b2f(x0.s[j]) * wt);
                sBn[(nc * 16 + 8 + j) * 72 + t] = f2b(b2f(x1.s[j]) * wt);
            }
        }
#pragma unroll
        for (int ti = 0; ti < 2; ti++)
#pragma unroll
            for (int tj = 0; tj < 2; tj++)
#pragma unroll
                for (int r = 0; r < 4; r++) {
                    int p = rowBlk + ti * 16 + quad * 4 + r;
                    int n = colBlk + tj * 16 + col;
                    sHb[p * 72 + n] = f2b(acc_h[ti][tj][r]);
                }
        __syncthreads();
        // (d) G = C @ B^T
        f32x4 g[2][2];
#pragma unroll
        for (int ti = 0; ti < 2; ti++)
#pragma unroll
            for (int tj = 0; tj < 2; tj++) g[ti][tj] = (f32x4){0.f, 0.f, 0.f, 0.f};
#pragma unroll
        for (int kb = 0; kb < 2; kb++) {
            bf16x8 ac[2], bc[2];
#pragma unroll
            for (int ti = 0; ti < 2; ti++)
                ac[ti] = *(const bf16x8*)(sCm + (rowBlk + ti * 16 + col) * 72 + kb * 32 + quad * 8);
#pragma unroll
            for (int tj = 0; tj < 2; tj++)
                bc[tj] = *(const bf16x8*)(sBtMs + (colBlk + tj * 16 + col) * 72 + kb * 32 + quad * 8);
#pragma unroll
            for (int ti = 0; ti < 2; ti++)
#pragma unroll
                for (int tj = 0; tj < 2; tj++)
                    g[ti][tj] = mfma16(ac[ti], bc[tj], g[ti][tj]);
        }
        __syncthreads();   // all waves done reading B before overwrite as M
        // (e) mask + decay -> M (s,t) into sBtMs
#pragma unroll
        for (int tj = 0; tj < 2; tj++) {
            int t_idx = colBlk + tj * 16 + col;
            float lt = sL[t_idx], dtt = sdt[t_idx];
#pragma unroll
            for (int ti = 0; ti < 2; ti++)
#pragma unroll
                for (int r = 0; r < 4; r++) {
                    int s_idx = rowBlk + ti * 16 + quad * 4 + r;
                    float m = (t_idx <= s_idx) ? g[ti][tj][r] * dtt * __expf(sL[s_idx] - lt) : 0.f;
                    sBtMs[s_idx * 72 + t_idx] = f2b(m);
                }
        }
        __syncthreads();
        // (f) Y = M @ X + (es*C) @ H^T
        f32x4 yv[2][2];
#pragma unroll
        for (int ti = 0; ti < 2; ti++)
#pragma unroll
            for (int tj = 0; tj < 2; tj++) yv[ti][tj] = (f32x4){0.f, 0.f, 0.f, 0.f};
#pragma unroll
        for (int kb = 0; kb < 2; kb++) {
            bf16x8 am[2], bxp[2];
#pragma unroll
            for (int ti = 0; ti < 2; ti++)
                am[ti] = *(const bf16x8*)(sBtMs + (rowBlk + ti * 16 + col) * 72 + kb * 32 + quad * 8);
#pragma unroll
            for (int tj = 0; tj < 2; tj++)
                bxp[tj] = *(const bf16x8*)(sXp + (colBlk + tj * 16 + col) * 72 + kb * 32 + quad * 8);
#pragma unroll
            for (int ti = 0; ti < 2; ti++)
#pragma unroll
                for (int tj = 0; tj < 2; tj++)
                    yv[ti][tj] = mfma16(am[ti], bxp[tj], yv[ti][tj]);
        }
        float es0 = sEs[rowBlk + col], es1 = sEs[rowBlk + 16 + col];
#pragma unroll
        for (int kb = 0; kb < 2; kb++) {
            bf16x8 acx[2], bhh[2];
#pragma unroll
            for (int ti = 0; ti < 2; ti++) {
                union { bf16x8 v; unsigned short s[8]; } a;
                a.v = *(const bf16x8*)(sCm + (rowBlk + ti * 16 + col) * 72 + kb * 32 + quad * 8);
                float es = ti ? es1 : es0;
#pragma unroll
                for (int j = 0; j < 8; j++) a.s[j] = f2b(b2f(a.s[j]) * es);
                acx[ti] = a.v;
            }
#pragma unroll
            for (int tj = 0; tj < 2; tj++)
                bhh[tj] = *(const bf16x8*)(sHb + (colBlk + tj * 16 + col) * 72 + kb * 32 + quad * 8);
#pragma unroll
            for (int ti = 0; ti < 2; ti++)
#pragma unroll
                for (int tj = 0; tj < 2; tj++)
                    yv[ti][tj] = mfma16(acx[ti], bhh[tj], yv[ti][tj]);
        }
        // (g) H = e_end*H + Xw^T @ B
        float e_end = __expf(Lend);
#pragma unroll
        for (int ti = 0; ti < 2; ti++)
#pragma unroll
            for (int tj = 0; tj < 2; tj++)
#pragma unroll
                for (int r = 0; r < 4; r++) acc_h[ti][tj][r] *= e_end;
#pragma unroll
        for (int kb = 0; kb < 2; kb++) {
            bf16x8 ax[2], bn[2];
#pragma unroll
            for (int ti = 0; ti < 2; ti++)
                ax[ti] = *(const bf16x8*)(sXp + (rowBlk + ti * 16 + col) * 72 + kb * 32 + quad * 8);
#pragma unroll
            for (int tj = 0; tj < 2; tj++)
                bn[tj] = *(const bf16x8*)(sBn + (colBlk + tj * 16 + col) * 72 + kb * 32 + quad * 8);
#pragma unroll
            for (int ti = 0; ti < 2; ti++)
#pragma unroll
                for (int tj = 0; tj < 2; tj++)
                    acc_h[ti][tj] = mfma16(ax[ti], bn[tj], acc_h[ti][tj]);
        }
        // (h) y epilogue: + D*x, store bf16
#pragma unroll
        for (int ti = 0; ti < 2; ti++)
#pragma unroll
            for (int tj = 0; tj < 2; tj++)
#pragma unroll
                for (int r = 0; r < 4; r++) {
                    int s_idx = rowBlk + ti * 16 + quad * 4 + r;
                    int p = colBlk + tj * 16 + col;
                    float xv = b2f(sXp[p * 72 + s_idx]);
                    float yo = yv[ti][tj][r] + Dh * xv;
                    yout[((long)(b * 2048 + l0 + s_idx)) * 8384 + 4096 + h * 64 + p] = f2b(yo);
                }
        __syncthreads();   // protect LDS reuse next sub-chunk
    }
}

// ====== kernel 6: gated RMSNorm: y2 = rmsnorm(y * silu(z)) * norm_w (bf16) ==
__global__ __launch_bounds__(256) void k_gatenorm(
    const unsigned short* __restrict__ zx, const float* __restrict__ nw,
    unsigned short* __restrict__ y2)
{
    int row = blockIdx.x, t = threadIdx.x;
    const unsigned short* zr = zx + (long)row * 8384;
    float v[16]; float ss = 0.f;
#pragma unroll
    for (int i = 0; i < 16; i++) {
        int c = t + i * 256;
        float z = b2f(zr[c]);
        float y = b2f(zr[4096 + c]);
        float g = y * (z / (1.f + expf(-z)));
        v[i] = g; ss += g * g;
    }
#pragma unroll
    for (int o = 32; o > 0; o >>= 1) ss += __shfl_down(ss, o);
    __shared__ float red[4];
    if ((t & 63) == 0) red[t >> 6] = ss;
    __syncthreads();
    float tot = red[0] + red[1] + red[2] + red[3];
    float scale = rsqrtf(tot * (1.0f / 4096.0f) + 1e-5f);
#pragma unroll
    for (int i = 0; i < 16; i++) {
        int c = t + i * 256;
        y2[(long)row * 4096 + c] = f2b(v[i] * scale * nw[c]);
    }
}

// ============================= launcher =====================================
extern "C" void kernel_launch(void* const* d_in, const int* in_sizes, int n_in,
                              void* d_out, int out_size, void* d_ws, size_t ws_size,
                              hipStream_t stream)
{
    const float* h    = (const float*)d_in[0]; // (2,2048,2048)
    const float* rmsw = (const float*)d_in[1]; // (2048)
    const float* w1   = (const float*)d_in[2]; // (8384,2048)
    const float* cw   = (const float*)d_in[3]; // (4224,4)
    const float* cbp  = (const float*)d_in[4]; // (4224)
    const float* dtb  = (const float*)d_in[5]; // (64)
    const float* alog = (const float*)d_in[6]; // (64)
    const float* Dv   = (const float*)d_in[7]; // (64)
    const float* nw   = (const float*)d_in[8]; // (4096)
    const float* w2   = (const float*)d_in[9]; // (2048,4096)

    char* ws = (char*)d_ws;
    // ws layout (peak 120,061,952 B — identical to R5's passing layout):
    //   [0, 68681728): zx bf16 4096x8384 (scan writes y into cols 4096..8192)
    //   [68681728, 103284736): w1b bf16 -> xbc bf16 4096x4224 -> y2 bf16
    //   [103284736, 111673344): Sbuf bf16 1024x4096
    //   [111673344, +4096):     dAt fp32 1024
    //   [103284736, 120061952): u before GEMM1; w2b after scan (Sbuf/dAt dead)
    unsigned short* zx    = (unsigned short*)ws;
    unsigned short* w1b   = (unsigned short*)(ws + 68681728L);
    unsigned short* xbc   = (unsigned short*)(ws + 68681728L);
    unsigned short* y2    = (unsigned short*)(ws + 68681728L);
    unsigned short* u     = (unsigned short*)(ws + 103284736L);
    unsigned short* Sbuf  = (unsigned short*)(ws + 103284736L);
    float*          dAt   = (float*)(ws + 111673344L);
    unsigned short* w2b   = (unsigned short*)(ws + 103284736L);
    float* outp = (float*)d_out;

    k_rmsnorm_in<<<4096, 256, 0, stream>>>(h, rmsw, u);
    k_cvt<<<8384, 256, 0, stream>>>(w1, w1b);
    // zx = u @ w1b^T : M=4096, N=8384 (66 tiles, clamped), K=2048
    k_gemm_bt<0><<<dim3(66, 32), 256, 0, stream>>>(u, w1b, 2048, 8384, zx, nullptr, 8384, nullptr);
    k_conv<<<dim3(33, 32, 2), 128, 0, stream>>>(zx, cw, cbp, xbc);
    k_chunk_state_mfma<<<1024, 256, 0, stream>>>(xbc, zx, dtb, alog, Sbuf, dAt);
    k_scan_chunk_mfma<<<1024, 256, 0, stream>>>(xbc, zx, dtb, alog, Dv, Sbuf, dAt, zx);
    k_gatenorm<<<4096, 256, 0, stream>>>(zx, nw, y2);
    k_cvt<<<4096, 256, 0, stream>>>(w2, w2b);
    // out = y2 @ w2b^T + residual : M=4096, N=2048, K=4096, fp32 out
    k_gemm_bt<1><<<dim3(16, 32), 256, 0, stream>>>(y2, w2b, 4096, 2048, nullptr, outp, 2048, h);
}

// Round 7
// 584.831 us; speedup vs baseline: 2.1330x; 1.0260x over previous
//
#include <hip/hip_runtime.h>
#include <stdint.h>

#define DEV static __device__ __forceinline__

typedef __attribute__((ext_vector_type(8))) __bf16 bf16x8;
typedef __attribute__((ext_vector_type(4))) float f32x4;
typedef __attribute__((ext_vector_type(16))) float f32x16;

// ---------- bf16 helpers ----------
DEV float b2f(unsigned short u) {
    union { unsigned int i; float f; } v; v.i = ((unsigned int)u) << 16; return v.f;
}
DEV unsigned short f2b(float f) {
    unsigned int u = __builtin_bit_cast(unsigned int, f);
    unsigned int r = (u + 0x7FFFu + ((u >> 16) & 1u)) >> 16;  // RNE
    return (unsigned short)r;
}
DEV f32x4 mfma16(bf16x8 a, bf16x8 b, f32x4 c) {
    return __builtin_amdgcn_mfma_f32_16x16x32_bf16(a, b, c, 0, 0, 0);
}
DEV f32x16 mfma32(bf16x8 a, bf16x8 b, f32x16 c) {
    return __builtin_amdgcn_mfma_f32_32x32x16_bf16(a, b, c, 0, 0, 0);
}

// ---------- async global->LDS, 16B per lane ----------
DEV void gload16(const void* g, void* l) {
    __builtin_amdgcn_global_load_lds(
        (const __attribute__((address_space(1))) void*)g,
        (__attribute__((address_space(3))) void*)l, 16, 0, 0);
}

// ============ kernel 0: fp32 -> bf16 copy (n multiple of 2048) ==============
__global__ __launch_bounds__(256) void k_cvt(
    const float* __restrict__ src, unsigned short* __restrict__ dst)
{
    long i = ((long)blockIdx.x * 256 + threadIdx.x) * 8;
    float4 a = *(const float4*)(src + i);
    float4 b = *(const float4*)(src + i + 4);
    union { uint4 v; unsigned short s[8]; } o;
    o.s[0] = f2b(a.x); o.s[1] = f2b(a.y); o.s[2] = f2b(a.z); o.s[3] = f2b(a.w);
    o.s[4] = f2b(b.x); o.s[5] = f2b(b.y); o.s[6] = f2b(b.z); o.s[7] = f2b(b.w);
    *(uint4*)(dst + i) = o.v;
}

// ================== kernel 1: RMSNorm of hidden -> u (bf16) =================
__global__ __launch_bounds__(256) void k_rmsnorm_in(
    const float* __restrict__ h, const float* __restrict__ w,
    unsigned short* __restrict__ u)
{
    int row = blockIdx.x, t = threadIdx.x;
    const float* hp = h + (long)row * 2048 + t * 8;
    float4 a = *(const float4*)hp;
    float4 b = *(const float4*)(hp + 4);
    float x[8] = {a.x, a.y, a.z, a.w, b.x, b.y, b.z, b.w};
    float ss = 0.f;
#pragma unroll
    for (int i = 0; i < 8; i++) ss += x[i] * x[i];
#pragma unroll
    for (int o = 32; o > 0; o >>= 1) ss += __shfl_down(ss, o);
    __shared__ float red[4];
    if ((t & 63) == 0) red[t >> 6] = ss;
    __syncthreads();
    float tot = red[0] + red[1] + red[2] + red[3];
    float scale = rsqrtf(tot * (1.0f / 2048.0f) + 1e-5f);
    float4 wa = *(const float4*)(w + t * 8);
    float4 wb = *(const float4*)(w + t * 8 + 4);
    float wv[8] = {wa.x, wa.y, wa.z, wa.w, wb.x, wb.y, wb.z, wb.w};
    union { uint4 v; unsigned short s[8]; } ow;
#pragma unroll
    for (int i = 0; i < 8; i++) ow.s[i] = f2b(x[i] * scale * wv[i]);
    *(uint4*)(u + (long)row * 2048 + t * 8) = ow.v;
}

// ================== GEMM: C[MxN] = A[MxK] * B[NxK]^T (bf16 in, fp32 acc) ====
// 128x128 tile, BK=32, 4 waves (2x2 of 64x64), 32x32x16 MFMA (2x2 per wave).
// Supertile swizzle: 8 M-tiles per supercolumn for L2 reuse of B.
// EPI 0: store bf16 to Cb.  EPI 1: store fp32 (acc + fp32 Res) to Cf.
template <int EPI>
__global__ __launch_bounds__(256) void k_gemm_bt(
    const unsigned short* __restrict__ A, const unsigned short* __restrict__ Bm,
    int K, int nvalid, unsigned short* __restrict__ Cb, float* __restrict__ Cf,
    int ldc, const float* __restrict__ Res)
{
    __shared__ __align__(16) unsigned short sA[128 * 32];
    __shared__ __align__(16) unsigned short sB[128 * 32];
    int t = threadIdx.x;
    int w = t >> 6, L = t & 63;

    // ---- supertile swizzle (gy must be multiple of 8; 32 here) ----
    int flat = blockIdx.y * gridDim.x + blockIdx.x;
    int per = gridDim.x * 8;
    int strip = flat / per;
    int rem = flat - strip * per;
    long m0 = (long)(strip * 8 + (rem & 7)) * 128;
    long n0 = (long)(rem >> 3) * 128;

    int rS = w * 32 + (L >> 2);
    int cS = (L & 3) * 8;
    long rB0 = n0 + rS;       if (rB0 >= nvalid) rB0 = nvalid - 1;
    long rB1 = n0 + rS + 16;  if (rB1 >= nvalid) rB1 = nvalid - 1;
    const unsigned short* gA0 = A + (m0 + rS) * K + cS;
    const unsigned short* gA1 = gA0 + 16L * K;
    const unsigned short* gB0 = Bm + rB0 * K + cS;
    const unsigned short* gB1 = Bm + rB1 * K + cS;
    unsigned short* lA0 = sA + (w * 32) * 32 + L * 8;
    unsigned short* lA1 = lA0 + 16 * 32;
    unsigned short* lB0 = sB + (w * 32) * 32 + L * 8;
    unsigned short* lB1 = lB0 + 16 * 32;

    int mw = (w >> 1) * 64, nw = (w & 1) * 64;
    // 32x32x16 A/B fragment: m(n)=lane&31, k=(lane>>5)*8+j
    const unsigned short* fA = sA + (mw + (L & 31)) * 32 + (L >> 5) * 8;
    const unsigned short* fB = sB + (nw + (L & 31)) * 32 + (L >> 5) * 8;

    f32x16 acc[2][2];
#pragma unroll
    for (int ti = 0; ti < 2; ti++)
#pragma unroll
        for (int tj = 0; tj < 2; tj++)
#pragma unroll
            for (int r = 0; r < 16; r++) acc[ti][tj][r] = 0.f;

    for (int kt = 0; kt < K; kt += 32) {
        gload16(gA0, lA0); gload16(gA1, lA1);
        gload16(gB0, lB0); gload16(gB1, lB1);
        gA0 += 32; gA1 += 32; gB0 += 32; gB1 += 32;
        __syncthreads();
#pragma unroll
        for (int kk = 0; kk < 2; kk++) {
            bf16x8 af[2], bf[2];
#pragma unroll
            for (int ti = 0; ti < 2; ti++)
                af[ti] = *(const bf16x8*)(fA + ti * 32 * 32 + kk * 16);
#pragma unroll
            for (int tj = 0; tj < 2; tj++)
                bf[tj] = *(const bf16x8*)(fB + tj * 32 * 32 + kk * 16);
#pragma unroll
            for (int ti = 0; ti < 2; ti++)
#pragma unroll
                for (int tj = 0; tj < 2; tj++)
                    acc[ti][tj] = mfma32(af[ti], bf[tj], acc[ti][tj]);
        }
        __syncthreads();
    }
    // C/D layout (m74/m101): col = lane&31, row = (reg&3) + 8*(reg>>2) + 4*(lane>>5)
    int colL = L & 31;
    int rL = (L >> 5) * 4;
#pragma unroll
    for (int ti = 0; ti < 2; ti++)
#pragma unroll
        for (int tj = 0; tj < 2; tj++) {
            long c = n0 + nw + tj * 32 + colL;
            if (c >= nvalid) continue;
#pragma unroll
            for (int r = 0; r < 16; r++) {
                long row = m0 + mw + ti * 32 + (r & 3) + 8 * (r >> 2) + rL;
                float v = acc[ti][tj][r];
                if (EPI == 0) Cb[row * ldc + c] = f2b(v);
                else          Cf[row * ldc + c] = v + Res[row * ldc + c];
            }
        }
}

// ======= kernel 4: depthwise causal conv(4) + bias + silu over xBC ==========
__global__ __launch_bounds__(128) void k_conv(
    const unsigned short* __restrict__ zx, const float* __restrict__ cw,
    const float* __restrict__ cb, unsigned short* __restrict__ xbc)
{
    int c = blockIdx.x * 128 + threadIdx.x;   // 0..4223
    int b = blockIdx.z;
    int l0 = blockIdx.y * 64;
    float w0 = cw[c * 4 + 0], w1 = cw[c * 4 + 1];
    float w2 = cw[c * 4 + 2], w3 = cw[c * 4 + 3];
    float bias = cb[c];
    const unsigned short* src = zx + ((long)b * 2048) * 8384 + 4096 + c;
    float xm3 = (l0 >= 3) ? b2f(src[(long)(l0 - 3) * 8384]) : 0.f;
    float xm2 = (l0 >= 2) ? b2f(src[(long)(l0 - 2) * 8384]) : 0.f;
    float xm1 = (l0 >= 1) ? b2f(src[(long)(l0 - 1) * 8384]) : 0.f;
    const unsigned short* s2 = src + (long)l0 * 8384;
    unsigned short* dst = xbc + ((long)(b * 2048 + l0)) * 4224 + c;
#pragma unroll 8
    for (int i = 0; i < 64; i++) {
        float xl = b2f(*s2); s2 += 8384;
        float a = xm3 * w0 + xm2 * w1 + xm1 * w2 + xl * w3 + bias;
        a = a / (1.f + expf(-a));      // silu
        *dst = f2b(a); dst += 4224;
        xm3 = xm2; xm2 = xm1; xm1 = xl;
    }
}

// ============ kernel 5a: per-chunk state via MFMA (pass 1) ==================
__global__ __launch_bounds__(256) void k_chunk_state_mfma(
    const unsigned short* __restrict__ xbc, const unsigned short* __restrict__ zxdt,
    const float* __restrict__ dt_bias, const float* __restrict__ A_log,
    unsigned short* __restrict__ Sbuf, float* __restrict__ dAtot)
{
    int blk = blockIdx.x;
    int c = blk & 7, bh = blk >> 3;
    int b = bh >> 6, h = bh & 63;
    int tid = threadIdx.x;
    int w = tid >> 6, L = tid & 63;
    int quad = L >> 4, col = L & 15;
    int rowBlk = (w >> 1) * 32, colBlk = (w & 1) * 32;
    __shared__ __align__(16) unsigned short sXp[64 * 72];  // X^T (p,t)
    __shared__ __align__(16) unsigned short sBn[64 * 72];  // scaled B^T (n,t)
    __shared__ float sdt[64], sL[64];
    float Ah = expf(A_log[h]);
    float dtb = dt_bias[h];
    f32x4 acc[2][2];
#pragma unroll
    for (int ti = 0; ti < 2; ti++)
#pragma unroll
        for (int tj = 0; tj < 2; tj++) acc[ti][tj] = (f32x4){0.f, 0.f, 0.f, 0.f};
    float sumL = 0.f;

    for (int sub = 0; sub < 4; sub++) {
        int l0 = c * 256 + sub * 64;
        // stage X transposed -> (p,t)
        {
            int t = tid >> 2, pc = tid & 3;
            const unsigned short* gX = xbc + (long)(b * 2048 + l0 + t) * 4224 + h * 64 + pc * 16;
            union { uint4 v; unsigned short s[8]; } x0, x1;
            x0.v = *(const uint4*)gX; x1.v = *(const uint4*)(gX + 8);
#pragma unroll
            for (int j = 0; j < 8; j++) {
                sXp[(pc * 16 + j) * 72 + t] = x0.s[j];
                sXp[(pc * 16 + 8 + j) * 72 + t] = x1.s[j];
            }
        }
        // dt, cumulative log-decay (wave 0)
        if (tid < 64) {
            float raw = b2f(zxdt[((long)(b * 2048 + l0 + tid)) * 8384 + 8320 + h]) + dtb;
            float dtv = (raw > 20.f) ? raw : log1pf(expf(raw));
            float cum = dtv;
#pragma unroll
            for (int off = 1; off < 64; off <<= 1) {
                float v = __shfl_up(cum, off);
                if (tid >= off) cum += v;
            }
            sdt[tid] = dtv;
            sL[tid] = -Ah * cum;
        }
        __syncthreads();
        float Lend = sL[63];
        // stage B transposed & scaled: Bn[n][t] = B[t][n] * dt_t * exp(Lend - L_t)
        {
            int t = tid >> 2, nc = tid & 3;
            float wt = sdt[t] * __expf(Lend - sL[t]);
            const unsigned short* gB = xbc + (long)(b * 2048 + l0 + t) * 4224 + 4096 + nc * 16;
            union { uint4 v; unsigned short s[8]; } x0, x1;
            x0.v = *(const uint4*)gB; x1.v = *(const uint4*)(gB + 8);
#pragma unroll
            for (int j = 0; j < 8; j++) {
                sBn[(nc * 16 + j) * 72 + t] = f2b(b2f(x0.s[j]) * wt);
                sBn[(nc * 16 + 8 + j) * 72 + t] = f2b(b2f(x1.s[j]) * wt);
            }
        }
        __syncthreads();
        float e_end = __expf(Lend);
        sumL += Lend;
#pragma unroll
        for (int ti = 0; ti < 2; ti++)
#pragma unroll
            for (int tj = 0; tj < 2; tj++)
#pragma unroll
                for (int r = 0; r < 4; r++) acc[ti][tj][r] *= e_end;
#pragma unroll
        for (int kb = 0; kb < 2; kb++) {
            bf16x8 ax[2], bx[2];
#pragma unroll
            for (int ti = 0; ti < 2; ti++)
                ax[ti] = *(const bf16x8*)(sXp + (rowBlk + ti * 16 + col) * 72 + kb * 32 + quad * 8);
#pragma unroll
            for (int tj = 0; tj < 2; tj++)
                bx[tj] = *(const bf16x8*)(sBn + (colBlk + tj * 16 + col) * 72 + kb * 32 + quad * 8);
#pragma unroll
            for (int ti = 0; ti < 2; ti++)
#pragma unroll
                for (int tj = 0; tj < 2; tj++)
                    acc[ti][tj] = mfma16(ax[ti], bx[tj], acc[ti][tj]);
        }
        __syncthreads();
    }
#pragma unroll
    for (int ti = 0; ti < 2; ti++)
#pragma unroll
        for (int tj = 0; tj < 2; tj++)
#pragma unroll
            for (int r = 0; r < 4; r++) {
                int p = rowBlk + ti * 16 + quad * 4 + r;
                int n = colBlk + tj * 16 + col;
                Sbuf[(long)blk * 4096 + p * 64 + n] = f2b(acc[ti][tj][r]);
            }
    if (tid == 0) dAtot[blk] = __expf(sumL);
}

// ============ kernel 5b: SSD intra-chunk via MFMA (pass 2) ==================
__global__ __launch_bounds__(256) void k_scan_chunk_mfma(
    const unsigned short* __restrict__ xbc, const unsigned short* __restrict__ zxdt,
    const float* __restrict__ dt_bias, const float* __restrict__ A_log,
    const float* __restrict__ Dv,
    const unsigned short* __restrict__ Sbuf, const float* __restrict__ dAtot,
    unsigned short* __restrict__ yout)
{
    int blk = blockIdx.x;
    int c = blk & 7, bh = blk >> 3;
    int b = bh >> 6, h = bh & 63;
    int tid = threadIdx.x;
    int w = tid >> 6, L = tid & 63;
    int quad = L >> 4, col = L & 15;
    int rowBlk = (w >> 1) * 32, colBlk = (w & 1) * 32;
    __shared__ __align__(16) unsigned short sCm[64 * 72];    // C (s,n)
    __shared__ __align__(16) unsigned short sBtMs[64 * 72];  // B (t,n) -> reused as M (s,t)
    __shared__ __align__(16) unsigned short sXp[64 * 72];    // X^T (p,t)
    __shared__ __align__(16) unsigned short sBn[64 * 72];    // scaled B^T (n,t)
    __shared__ __align__(16) unsigned short sHb[64 * 72];    // H (p,n) bf16
    __shared__ float sdt[64], sL[64], sEs[64];
    float Ah = expf(A_log[h]);
    float dtb = dt_bias[h];
    float Dh = Dv[h];

    f32x4 acc_h[2][2];
#pragma unroll
    for (int ti = 0; ti < 2; ti++)
#pragma unroll
        for (int tj = 0; tj < 2; tj++) acc_h[ti][tj] = (f32x4){0.f, 0.f, 0.f, 0.f};
    int sb = bh * 8;
    for (int j = 0; j < c; j++) {
        float d = dAtot[sb + j];
        const unsigned short* Sp = Sbuf + (long)(sb + j) * 4096;
#pragma unroll
        for (int ti = 0; ti < 2; ti++)
#pragma unroll
            for (int tj = 0; tj < 2; tj++)
#pragma unroll
                for (int r = 0; r < 4; r++) {
                    int p = rowBlk + ti * 16 + quad * 4 + r;
                    int n = colBlk + tj * 16 + col;
                    acc_h[ti][tj][r] = acc_h[ti][tj][r] * d + b2f(Sp[p * 64 + n]);
                }
    }

    for (int sub = 0; sub < 4; sub++) {
        int l0 = c * 256 + sub * 64;
        // (a) stage C (s,n) and B (t,n), stride-72 rows
        {
            int row = tid >> 2, c4 = tid & 3;
            const unsigned short* gR = xbc + (long)(b * 2048 + l0 + row) * 4224;
            uint4 v0 = *(const uint4*)(gR + 4160 + c4 * 8);
            uint4 v1 = *(const uint4*)(gR + 4160 + (c4 + 4) * 8);
            *(uint4*)(sCm + row * 72 + c4 * 8) = v0;
            *(uint4*)(sCm + row * 72 + (c4 + 4) * 8) = v1;
            uint4 w0 = *(const uint4*)(gR + 4096 + c4 * 8);
            uint4 w1 = *(const uint4*)(gR + 4096 + (c4 + 4) * 8);
            *(uint4*)(sBtMs + row * 72 + c4 * 8) = w0;
            *(uint4*)(sBtMs + row * 72 + (c4 + 4) * 8) = w1;
        }
        // stage X transposed
        {
            int t = tid >> 2, pc = tid & 3;
            const unsigned short* gX = xbc + (long)(b * 2048 + l0 + t) * 4224 + h * 64 + pc * 16;
            union { uint4 v; unsigned short s[8]; } x0, x1;
            x0.v = *(const uint4*)gX; x1.v = *(const uint4*)(gX + 8);
#pragma unroll
            for (int j = 0; j < 8; j++) {
                sXp[(pc * 16 + j) * 72 + t] = x0.s[j];
                sXp[(pc * 16 + 8 + j) * 72 + t] = x1.s[j];
            }
        }
        // (b) dt / L / exp(L)
        if (tid < 64) {
            float raw = b2f(zxdt[((long)(b * 2048 + l0 + tid)) * 8384 + 8320 + h]) + dtb;
            float dtv = (raw > 20.f) ? raw : log1pf(expf(raw));
            float cum = dtv;
#pragma unroll
            for (int off = 1; off < 64; off <<= 1) {
                float v = __shfl_up(cum, off);
                if (tid >= off) cum += v;
            }
            sdt[tid] = dtv;
            float l = -Ah * cum;
            sL[tid] = l;
            sEs[tid] = __expf(l);
        }
        __syncthreads();
        float Lend = sL[63];
        // (c) stage scaled-transposed B; write H (bf16) for Ycross
        {
            int t = tid >> 2, nc = tid & 3;
            float wt = sdt[t] * __expf(Lend - sL[t]);
            const unsigned short* gB = xbc + (long)(b * 2048 + l0 + t) * 4224 + 4096 + nc * 16;
            union { uint4 v; unsigned short s[8]; } x0, x1;
            x0.v = *(const uint4*)gB; x1.v = *(const uint4*)(gB + 8);
#pragma unroll
            for (int j = 0; j < 8; j++) {
                sBn[(nc * 16 + j) * 72 + t] = f2b(b2f(x0.s[j]) * wt);
                sBn[(nc * 16 + 8 + j) * 72 + t] = f2b(b2f(x1.s[j]) * wt);
            }
        }
#pragma unroll
        for (int ti = 0; ti < 2; ti++)
#pragma unroll
            for (int tj = 0; tj < 2; tj++)
#pragma unroll
                for (int r = 0; r < 4; r++) {
                    int p = rowBlk + ti * 16 + quad * 4 + r;
                    int n = colBlk + tj * 16 + col;
                    sHb[p * 72 + n] = f2b(acc_h[ti][tj][r]);
                }
        __syncthreads();
        // (d) G = C @ B^T
        f32x4 g[2][2];
#pragma unroll
        for (int ti = 0; ti < 2; ti++)
#pragma unroll
            for (int tj = 0; tj < 2; tj++) g[ti][tj] = (f32x4){0.f, 0.f, 0.f, 0.f};
#pragma unroll
        for (int kb = 0; kb < 2; kb++) {
            bf16x8 ac[2], bc[2];
#pragma unroll
            for (int ti = 0; ti < 2; ti++)
                ac[ti] = *(const bf16x8*)(sCm + (rowBlk + ti * 16 + col) * 72 + kb * 32 + quad * 8);
#pragma unroll
            for (int tj = 0; tj < 2; tj++)
                bc[tj] = *(const bf16x8*)(sBtMs + (colBlk + tj * 16 + col) * 72 + kb * 32 + quad * 8);
#pragma unroll
            for (int ti = 0; ti < 2; ti++)
#pragma unroll
                for (int tj = 0; tj < 2; tj++)
                    g[ti][tj] = mfma16(ac[ti], bc[tj], g[ti][tj]);
        }
        __syncthreads();   // all waves done reading B before overwrite as M
        // (e) mask + decay -> M (s,t) into sBtMs
#pragma unroll
        for (int tj = 0; tj < 2; tj++) {
            int t_idx = colBlk + tj * 16 + col;
            float lt = sL[t_idx], dtt = sdt[t_idx];
#pragma unroll
            for (int ti = 0; ti < 2; ti++)
#pragma unroll
                for (int r = 0; r < 4; r++) {
                    int s_idx = rowBlk + ti * 16 + quad * 4 + r;
                    float m = (t_idx <= s_idx) ? g[ti][tj][r] * dtt * __expf(sL[s_idx] - lt) : 0.f;
                    sBtMs[s_idx * 72 + t_idx] = f2b(m);
                }
        }
        __syncthreads();
        // (f) Y = M @ X + (es*C) @ H^T
        f32x4 yv[2][2];
#pragma unroll
        for (int ti = 0; ti < 2; ti++)
#pragma unroll
            for (int tj = 0; tj < 2; tj++) yv[ti][tj] = (f32x4){0.f, 0.f, 0.f, 0.f};
#pragma unroll
        for (int kb = 0; kb < 2; kb++) {
            bf16x8 am[2], bxp[2];
#pragma unroll
            for (int ti = 0; ti < 2; ti++)
                am[ti] = *(const bf16x8*)(sBtMs + (rowBlk + ti * 16 + col) * 72 + kb * 32 + quad * 8);
#pragma unroll
            for (int tj = 0; tj < 2; tj++)
                bxp[tj] = *(const bf16x8*)(sXp + (colBlk + tj * 16 + col) * 72 + kb * 32 + quad * 8);
#pragma unroll
            for (int ti = 0; ti < 2; ti++)
#pragma unroll
                for (int tj = 0; tj < 2; tj++)
                    yv[ti][tj] = mfma16(am[ti], bxp[tj], yv[ti][tj]);
        }
        float es0 = sEs[rowBlk + col], es1 = sEs[rowBlk + 16 + col];
#pragma unroll
        for (int kb = 0; kb < 2; kb++) {
            bf16x8 acx[2], bhh[2];
#pragma unroll
            for (int ti = 0; ti < 2; ti++) {
                union { bf16x8 v; unsigned short s[8]; } a;
                a.v = *(const bf16x8*)(sCm + (rowBlk + ti * 16 + col) * 72 + kb * 32 + quad * 8);
                float es = ti ? es1 : es0;
#pragma unroll
                for (int j = 0; j < 8; j++) a.s[j] = f2b(b2f(a.s[j]) * es);
                acx[ti] = a.v;
            }
#pragma unroll
            for (int tj = 0; tj < 2; tj++)
                bhh[tj] = *(const bf16x8*)(sHb + (colBlk + tj * 16 + col) * 72 + kb * 32 + quad * 8);
#pragma unroll
            for (int ti = 0; ti < 2; ti++)
#pragma unroll
                for (int tj = 0; tj < 2; tj++)
                    yv[ti][tj] = mfma16(acx[ti], bhh[tj], yv[ti][tj]);
        }
        // (g) H = e_end*H + Xw^T @ B
        float e_end = __expf(Lend);
#pragma unroll
        for (int ti = 0; ti < 2; ti++)
#pragma unroll
            for (int tj = 0; tj < 2; tj++)
#pragma unroll
                for (int r = 0; r < 4; r++) acc_h[ti][tj][r] *= e_end;
#pragma unroll
        for (int kb = 0; kb < 2; kb++) {
            bf16x8 ax[2], bn[2];
#pragma unroll
            for (int ti = 0; ti < 2; ti++)
                ax[ti] = *(const bf16x8*)(sXp + (rowBlk + ti * 16 + col) * 72 + kb * 32 + quad * 8);
#pragma unroll
            for (int tj = 0; tj < 2; tj++)
                bn[tj] = *(const bf16x8*)(sBn + (colBlk + tj * 16 + col) * 72 + kb * 32 + quad * 8);
#pragma unroll
            for (int ti = 0; ti < 2; ti++)
#pragma unroll
                for (int tj = 0; tj < 2; tj++)
                    acc_h[ti][tj] = mfma16(ax[ti], bn[tj], acc_h[ti][tj]);
        }
        // (h) y epilogue: + D*x, store bf16
#pragma unroll
        for (int ti = 0; ti < 2; ti++)
#pragma unroll
            for (int tj = 0; tj < 2; tj++)
#pragma unroll
                for (int r = 0; r < 4; r++) {
                    int s_idx = rowBlk + ti * 16 + quad * 4 + r;
                    int p = colBlk + tj * 16 + col;
                    float xv = b2f(sXp[p * 72 + s_idx]);
                    float yo = yv[ti][tj][r] + Dh * xv;
                    yout[((long)(b * 2048 + l0 + s_idx)) * 8384 + 4096 + h * 64 + p] = f2b(yo);
                }
        __syncthreads();   // protect LDS reuse next sub-chunk
    }
}

// ====== kernel 6: gated RMSNorm: y2 = rmsnorm(y * silu(z)) * norm_w (bf16) ==
__global__ __launch_bounds__(256) void k_gatenorm(
    const unsigned short* __restrict__ zx, const float* __restrict__ nw,
    unsigned short* __restrict__ y2)
{
    int row = blockIdx.x, t = threadIdx.x;
    const unsigned short* zr = zx + (long)row * 8384;
    float v[16]; float ss = 0.f;
#pragma unroll
    for (int i = 0; i < 16; i++) {
        int c = t + i * 256;
        float z = b2f(zr[c]);
        float y = b2f(zr[4096 + c]);
        float g = y * (z / (1.f + expf(-z)));
        v[i] = g; ss += g * g;
    }
#pragma unroll
    for (int o = 32; o > 0; o >>= 1) ss += __shfl_down(ss, o);
    __shared__ float red[4];
    if ((t & 63) == 0) red[t >> 6] = ss;
    __syncthreads();
    float tot = red[0] + red[1] + red[2] + red[3];
    float scale = rsqrtf(tot * (1.0f / 4096.0f) + 1e-5f);
#pragma unroll
    for (int i = 0; i < 16; i++) {
        int c = t + i * 256;
        y2[(long)row * 4096 + c] = f2b(v[i] * scale * nw[c]);
    }
}

// ============================= launcher =====================================
extern "C" void kernel_launch(void* const* d_in, const int* in_sizes, int n_in,
                              void* d_out, int out_size, void* d_ws, size_t ws_size,
                              hipStream_t stream)
{
    const float* h    = (const float*)d_in[0]; // (2,2048,2048)
    const float* rmsw = (const float*)d_in[1]; // (2048)
    const float* w1   = (const float*)d_in[2]; // (8384,2048)
    const float* cw   = (const float*)d_in[3]; // (4224,4)
    const float* cbp  = (const float*)d_in[4]; // (4224)
    const float* dtb  = (const float*)d_in[5]; // (64)
    const float* alog = (const float*)d_in[6]; // (64)
    const float* Dv   = (const float*)d_in[7]; // (64)
    const float* nw   = (const float*)d_in[8]; // (4096)
    const float* w2   = (const float*)d_in[9]; // (2048,4096)

    char* ws = (char*)d_ws;
    // ws layout (peak 120,061,952 B — identical to R5/R6 passing layout):
    //   [0, 68681728): zx bf16 4096x8384 (scan writes y into cols 4096..8192)
    //   [68681728, 103284736): w1b bf16 -> xbc bf16 4096x4224 -> y2 bf16
    //   [103284736, 111673344): Sbuf bf16 1024x4096
    //   [111673344, +4096):     dAt fp32 1024
    //   [103284736, 120061952): u before GEMM1; w2b after scan (Sbuf/dAt dead)
    unsigned short* zx    = (unsigned short*)ws;
    unsigned short* w1b   = (unsigned short*)(ws + 68681728L);
    unsigned short* xbc   = (unsigned short*)(ws + 68681728L);
    unsigned short* y2    = (unsigned short*)(ws + 68681728L);
    unsigned short* u     = (unsigned short*)(ws + 103284736L);
    unsigned short* Sbuf  = (unsigned short*)(ws + 103284736L);
    float*          dAt   = (float*)(ws + 111673344L);
    unsigned short* w2b   = (unsigned short*)(ws + 103284736L);
    float* outp = (float*)d_out;

    k_rmsnorm_in<<<4096, 256, 0, stream>>>(h, rmsw, u);
    k_cvt<<<8384, 256, 0, stream>>>(w1, w1b);
    // zx = u @ w1b^T : M=4096, N=8384 (66 tiles, clamped), K=2048
    k_gemm_bt<0><<<dim3(66, 32), 256, 0, stream>>>(u, w1b, 2048, 8384, zx, nullptr, 8384, nullptr);
    k_conv<<<dim3(33, 32, 2), 128, 0, stream>>>(zx, cw, cbp, xbc);
    k_chunk_state_mfma<<<1024, 256, 0, stream>>>(xbc, zx, dtb, alog, Sbuf, dAt);
    k_scan_chunk_mfma<<<1024, 256, 0, stream>>>(xbc, zx, dtb, alog, Dv, Sbuf, dAt, zx);
    k_gatenorm<<<4096, 256, 0, stream>>>(zx, nw, y2);
    k_cvt<<<4096, 256, 0, stream>>>(w2, w2b);
    // out = y2 @ w2b^T + residual : M=4096, N=2048, K=4096, fp32 out
    k_gemm_bt<1><<<dim3(16, 32), 256, 0, stream>>>(y2, w2b, 4096, 2048, nullptr, outp, 2048, h);
}